// Round 6
// baseline (661.356 us; speedup 1.0000x reference)
//
#include <hip/hip_runtime.h>

#define CI 4
#define CO 8
#define TT 8
#define S 96
#define S2 (S*S)
#define SLICE (S*S*S)          // 884736 elements per (c,t) slice
#define NSLICE (CI*TT)         // 32 slices
#define EPS 1e-5f
#define WTOT (CO*CI*81)        // 10368 weight elements
#define WS_WT_OFF 64           // float offset of transposed weights in ws

// ws layout (floats): [0:32) sum, [32:64) sumsq, [64:64+WTOT) transposed weights

// Stats + (fused) weight transpose. Transpose target layout:
// [ci][kt][kd][kh][co][kw] -> per (ci,kt): 9 contiguous 24-float groups.
__global__ __launch_bounds__(256) void stats_partial(
        const float* __restrict__ x, float* __restrict__ ws,
        const float* __restrict__ w, float* __restrict__ wt) {
    const int slice = blockIdx.y;
    const float4* p = reinterpret_cast<const float4*>(x + (size_t)slice * SLICE);
    const int n4 = SLICE / 4;  // 221184
    float s = 0.f, ss = 0.f;
    for (int i = blockIdx.x * blockDim.x + threadIdx.x; i < n4;
         i += gridDim.x * blockDim.x) {
        float4 v = p[i];
        s  += v.x + v.y + v.z + v.w;
        ss += v.x*v.x + v.y*v.y + v.z*v.z + v.w*v.w;
    }
    #pragma unroll
    for (int off = 32; off > 0; off >>= 1) {
        s  += __shfl_down(s, off);
        ss += __shfl_down(ss, off);
    }
    __shared__ float ls[4], lss[4];
    const int lane = threadIdx.x & 63, wid = threadIdx.x >> 6;
    if (lane == 0) { ls[wid] = s; lss[wid] = ss; }
    __syncthreads();
    if (threadIdx.x == 0) {
        float ts  = ls[0] + ls[1] + ls[2] + ls[3];
        float tss = lss[0] + lss[1] + lss[2] + lss[3];
        atomicAdd(&ws[slice], ts);
        atomicAdd(&ws[NSLICE + slice], tss);
    }
    // fused weight transpose (y==0 blocks only; 64*256 threads >= WTOT)
    if (wt != nullptr && blockIdx.y == 0) {
        for (int i = blockIdx.x * blockDim.x + threadIdx.x; i < WTOT;
             i += 64 * 256) {
            int kw = i % 3; int r = i / 3;
            int co = r % CO; r /= CO;
            int kh = r % 3;  r /= 3;
            int kd = r % 3;  r /= 3;
            int kt = r % 3;  r /= 3;
            int ci = r;
            wt[i] = w[((((co * CI + ci) * 3 + kt) * 3 + kd) * 3 + kh) * 3 + kw];
        }
    }
}

// Register-blocked fused norm+relu+conv4d.
// Thread tile: 4 w (float4) x 2 h x 8 co = 64 accumulators.
// Block (24,8): 96 w x 16 h at fixed (d,t). 1-D grid 4608, XCD-swizzled:
//   xcd = bid&7 owns d in [xcd*12, xcd*12+12) x all t (balanced; rolling
//   L2 working set ~3.4 MB < 4 MB per-XCD L2).
// Row loads: 3-buffer kd pipeline (R4). Weights (TW): 9x24-float groups per
// (ci,kt), software-pipelined one group ahead in SSA arrays.
template <bool TW>
__global__ __launch_bounds__(192, 3) void conv4d_fused(
        const float* __restrict__ x, const float* __restrict__ wsrc,
        const float* __restrict__ bias, const float* __restrict__ ws,
        float* __restrict__ out) {
    // swizzled block decode
    const int o   = blockIdx.x;            // 0..4607
    const int xcd = o & 7;
    const int ii  = o >> 3;                // 0..575
    const int d   = xcd * 12 + ii / 48;
    const int rr  = ii % 48;
    const int t   = rr / 6;
    const int hb  = rr % 6;

    const int lane = threadIdx.x;          // 0..23 -> w chunk
    const int ty   = threadIdx.y;          // 0..7
    const int w0   = lane << 2;            // 0,4,...,92
    const int h0   = (hb * 8 + ty) * 2;    // first of 2 h rows

    float acc[2][CO][4];
    #pragma unroll
    for (int p = 0; p < 2; p++)
        #pragma unroll
        for (int co = 0; co < CO; co++)
            #pragma unroll
            for (int j = 0; j < 4; j++) acc[p][co][j] = 0.f;

    const bool wlb = (lane > 0), wrb = (lane < 23);
    const int  om1 = wlb ? -1 : 0;         // clamped: loads always in-range
    const int  op4 = wrb ?  4 : 3;
    const float fwl = wlb ? 1.f : 0.f, fwr = wrb ? 1.f : 0.f;
    const float inv_n = 1.f / (float)SLICE;

    // d-edge (uniform per block) and h-edge (per thread) masks/clamps
    const int dm1 = d > 0 ? d - 1 : 0;
    const int dp1 = d < S - 1 ? d + 1 : S - 1;
    const float md0 = d > 0 ? 1.f : 0.f;
    const float md2 = d < S - 1 ? 1.f : 0.f;
    float mr0, mr1, mr2, mr3;
    int o0, o1, o2, o3;
    {
        const int hh0 = h0 - 1, hh3 = h0 + 2;
        mr0 = ((unsigned)hh0 < S) ? 1.f : 0.f;
        mr1 = 1.f; mr2 = 1.f;
        mr3 = ((unsigned)hh3 < S) ? 1.f : 0.f;
        const int hc0 = hh0 < 0 ? 0 : hh0;
        const int hc3 = hh3 > S - 1 ? S - 1 : hh3;
        o0 = hc0 * S + w0; o1 = h0 * S + w0;
        o2 = (h0 + 1) * S + w0; o3 = hc3 * S + w0;
    }

    // kt range for this t (uniform): tt = t+kt-1 in [0,TT)
    const int ktlo = (t == 0) ? 1 : 0;
    const int kthi = (t == TT - 1) ? 1 : 2;
    const int nkt  = kthi - ktlo + 1;
    const int niter = CI * nkt;

    // ---- named register buffers (12 values each) ----
    #define DECL_BUF(N) \
        float4 f##N##0, f##N##1, f##N##2, f##N##3; \
        float e##N##00, e##N##01, e##N##02, e##N##03; \
        float e##N##10, e##N##11, e##N##12, e##N##13;
    DECL_BUF(A) DECL_BUF(B) DECL_BUF(C)

    #define LOAD_BUF(N, XP) do { \
        const float* _r0 = (XP) + o0; const float* _r1 = (XP) + o1; \
        const float* _r2 = (XP) + o2; const float* _r3 = (XP) + o3; \
        f##N##0 = *reinterpret_cast<const float4*>(_r0); \
        f##N##1 = *reinterpret_cast<const float4*>(_r1); \
        f##N##2 = *reinterpret_cast<const float4*>(_r2); \
        f##N##3 = *reinterpret_cast<const float4*>(_r3); \
        e##N##00 = _r0[om1]; e##N##01 = _r1[om1]; \
        e##N##02 = _r2[om1]; e##N##03 = _r3[om1]; \
        e##N##10 = _r0[op4]; e##N##11 = _r1[op4]; \
        e##N##12 = _r2[op4]; e##N##13 = _r3[op4]; \
    } while (0)

    #define NORM_ROW(NN, N, R, MR, MD) do { \
        const float m_ = (MR) * (MD); \
        const float rs = rstd * m_, nm = nmr * m_; \
        NN[R][0] = fwl * fmaxf(fmaf(e##N##0##R, rs, nm), 0.f); \
        NN[R][1] =       fmaxf(fmaf(f##N##R.x,  rs, nm), 0.f); \
        NN[R][2] =       fmaxf(fmaf(f##N##R.y,  rs, nm), 0.f); \
        NN[R][3] =       fmaxf(fmaf(f##N##R.z,  rs, nm), 0.f); \
        NN[R][4] =       fmaxf(fmaf(f##N##R.w,  rs, nm), 0.f); \
        NN[R][5] = fwr * fmaxf(fmaf(e##N##1##R, rs, nm), 0.f); \
    } while (0)

    #define NORM4(NN, N, MD) do { \
        NORM_ROW(NN, N, 0, mr0, MD); NORM_ROW(NN, N, 1, mr1, MD); \
        NORM_ROW(NN, N, 2, mr2, MD); NORM_ROW(NN, N, 3, mr3, MD); \
    } while (0)

    // load one 24-float weight group into a constant-indexed array (SROA-safe)
    #define WLOAD(DST, PTR) do { \
        const float4* _w4 = reinterpret_cast<const float4*>(PTR); \
        float4 _a = _w4[0], _b = _w4[1], _c = _w4[2]; \
        float4 _d4 = _w4[3], _e = _w4[4], _f = _w4[5]; \
        DST[0]=_a.x;   DST[1]=_a.y;   DST[2]=_a.z;   DST[3]=_a.w;  \
        DST[4]=_b.x;   DST[5]=_b.y;   DST[6]=_b.z;   DST[7]=_b.w;  \
        DST[8]=_c.x;   DST[9]=_c.y;   DST[10]=_c.z;  DST[11]=_c.w; \
        DST[12]=_d4.x; DST[13]=_d4.y; DST[14]=_d4.z; DST[15]=_d4.w;\
        DST[16]=_e.x;  DST[17]=_e.y;  DST[18]=_e.z;  DST[19]=_e.w; \
        DST[20]=_f.x;  DST[21]=_f.y;  DST[22]=_f.z;  DST[23]=_f.w; \
    } while (0)

    // one kh tap-set; per-acc order (q ascending within kh) == R5 bit-exact
    #define PHASE(NN, KH, WARR) do { \
        _Pragma("unroll") \
        for (int q = 0; q < 3; q++) { \
            _Pragma("unroll") \
            for (int co = 0; co < CO; co++) { \
                const float k_ = WARR[co * 3 + q]; \
                _Pragma("unroll") \
                for (int j = 0; j < 4; j++) { \
                    acc[0][co][j] = fmaf(NN[KH][j + q],     k_, acc[0][co][j]); \
                    acc[1][co][j] = fmaf(NN[KH + 1][j + q], k_, acc[1][co][j]); \
                } \
            } \
        } \
    } while (0)

    // old-style compute (weights read in-loop) for the TW=false fallback
    #define COMPUTE_OLD(NN, WP) do { \
        _Pragma("unroll") \
        for (int kh = 0; kh < 3; kh++) { \
            _Pragma("unroll") \
            for (int q = 0; q < 3; q++) { \
                _Pragma("unroll") \
                for (int co = 0; co < CO; co++) { \
                    const float k_ = (WP)[co * (CI * 81) + kh * 3 + q]; \
                    _Pragma("unroll") \
                    for (int j = 0; j < 4; j++) { \
                        acc[0][co][j] = fmaf(NN[kh][j + q],     k_, acc[0][co][j]); \
                        acc[1][co][j] = fmaf(NN[kh + 1][j + q], k_, acc[1][co][j]); \
                    } \
                } \
            } \
        } \
    } while (0)

    // ---- prologue: params + first two stage loads for (ci=0, kt=ktlo) ----
    int ci = 0, kt = ktlo;
    int sl = ci * TT + (t + kt - 1);
    const float* xs = x + (size_t)sl * SLICE;
    const float* xp2;
    float rstd, nmr;
    {
        const float mean = ws[sl] * inv_n;
        const float var  = ws[NSLICE + sl] * inv_n - mean * mean;
        rstd = rsqrtf(var + EPS);
        nmr  = -mean * rstd;
    }
    const float* wp = TW ? (wsrc + (ci * 3 + kt) * 216)
                         : (wsrc + ci * 81 + kt * 27);
    xp2 = xs + (size_t)dp1 * S2;
    LOAD_BUF(A, xs + (size_t)dm1 * S2);   // kd0
    LOAD_BUF(B, xs + (size_t)d   * S2);   // kd1

    for (int it = 0; it < niter; it++) {
        // advance (uniform scalar); clamp at the end (loads wasted, unread)
        int kt_n = kt, ci_n = ci;
        if (it + 1 < niter) {
            kt_n = kt + 1;
            if (kt_n > kthi) { kt_n = ktlo; ci_n = ci + 1; }
        }
        const int sl_n = ci_n * TT + (t + kt_n - 1);
        const float* xs_n = x + (size_t)sl_n * SLICE;
        const float mean_n = ws[sl_n] * inv_n;
        const float var_n  = ws[NSLICE + sl_n] * inv_n - mean_n * mean_n;
        const float rstd_n = rsqrtf(var_n + EPS);
        const float nmr_n  = -mean_n * rstd_n;
        const float* wp_n = TW ? (wsrc + (ci_n * 3 + kt_n) * 216)
                               : (wsrc + ci_n * 81 + kt_n * 27);

        if constexpr (TW) {
            float wg0[24]; WLOAD(wg0, wp);                 // exposed once/iter
            LOAD_BUF(C, xp2);                              // kd2 of current

            float nnA[4][6]; NORM4(nnA, A, md0);           // ---- kd0 ----
            float wg1[24]; WLOAD(wg1, wp + 24);  PHASE(nnA, 0, wg0);
            float wg2[24]; WLOAD(wg2, wp + 48);  PHASE(nnA, 1, wg1);
            float wg3[24]; WLOAD(wg3, wp + 72);  PHASE(nnA, 2, wg2);

            LOAD_BUF(A, xs_n + (size_t)dm1 * S2);          // next kd0

            float nnB[4][6]; NORM4(nnB, B, 1.f);           // ---- kd1 ----
            float wg4[24]; WLOAD(wg4, wp + 96);  PHASE(nnB, 0, wg3);
            float wg5[24]; WLOAD(wg5, wp + 120); PHASE(nnB, 1, wg4);
            float wg6[24]; WLOAD(wg6, wp + 144); PHASE(nnB, 2, wg5);

            LOAD_BUF(B, xs_n + (size_t)d * S2);            // next kd1

            float nnC[4][6]; NORM4(nnC, C, md2);           // ---- kd2 ----
            float wg7[24]; WLOAD(wg7, wp + 168); PHASE(nnC, 0, wg6);
            float wg8[24]; WLOAD(wg8, wp + 192); PHASE(nnC, 1, wg7);
                                                 PHASE(nnC, 2, wg8);
        } else {
            LOAD_BUF(C, xp2);
            float nnA[4][6]; NORM4(nnA, A, md0);
            COMPUTE_OLD(nnA, wp);
            LOAD_BUF(A, xs_n + (size_t)dm1 * S2);
            float nnB[4][6]; NORM4(nnB, B, 1.f);
            COMPUTE_OLD(nnB, wp + 9);
            LOAD_BUF(B, xs_n + (size_t)d * S2);
            float nnC[4][6]; NORM4(nnC, C, md2);
            COMPUTE_OLD(nnC, wp + 18);
        }

        // rotate params
        rstd = rstd_n; nmr = nmr_n; wp = wp_n;
        xp2 = xs_n + (size_t)dp1 * S2;
        ci = ci_n; kt = kt_n;
    }

    #undef DECL_BUF
    #undef LOAD_BUF
    #undef NORM_ROW
    #undef NORM4
    #undef WLOAD
    #undef PHASE
    #undef COMPUTE_OLD

    // out shape (1, CO, T, D, H, W); float4 stores (w0 is 16B-aligned)
    #pragma unroll
    for (int p = 0; p < 2; p++) {
        const size_t obase = (((size_t)t * S + d) * S + (h0 + p)) * S + w0;
        #pragma unroll
        for (int co = 0; co < CO; co++) {
            const float bb = bias[co];
            float4 ov;
            ov.x = acc[p][co][0] + bb;
            ov.y = acc[p][co][1] + bb;
            ov.z = acc[p][co][2] + bb;
            ov.w = acc[p][co][3] + bb;
            *reinterpret_cast<float4*>(out + (size_t)co * ((size_t)TT * SLICE) + obase) = ov;
        }
    }
}

extern "C" void kernel_launch(void* const* d_in, const int* in_sizes, int n_in,
                              void* d_out, int out_size, void* d_ws, size_t ws_size,
                              hipStream_t stream) {
    const float* x   = (const float*)d_in[0];
    const float* w   = (const float*)d_in[1];
    const float* b   = (const float*)d_in[2];
    float* out = (float*)d_out;
    float* ws  = (float*)d_ws;

    const bool tw = ws_size >= (size_t)(WS_WT_OFF + WTOT) * sizeof(float);
    float* wt = tw ? (ws + WS_WT_OFF) : nullptr;

    // zero the atomic accumulators (ws is poisoned before every launch)
    hipMemsetAsync(ws, 0, 2 * NSLICE * sizeof(float), stream);
    stats_partial<<<dim3(64, NSLICE), 256, 0, stream>>>(x, ws, w, wt);
    if (tw) {
        conv4d_fused<true><<<S * (S / 16) * TT, dim3(24, 8, 1), 0, stream>>>(
                x, ws + WS_WT_OFF, b, ws, out);
    } else {
        conv4d_fused<false><<<S * (S / 16) * TT, dim3(24, 8, 1), 0, stream>>>(
                x, w, b, ws, out);
    }
}